// Round 16
// baseline (83.382 us; speedup 1.0000x reference)
//
#include <hip/hip_runtime.h>
#include <hip/hip_fp16.h>

#define B_ 4
#define C_ 16
#define H_ 64
#define W_ 64
#define F_ 32
#define S_ 66
#define CHW_ (S_ * S_)                 // padded plane = 4356
#define XN_ (B_ * 8 * CHW_)            // packed x entries (half2 ch-pairs) = 139392
#define CPAIR 90                       // half2 per (f,pair): 9 taps x (6 n + 4 d)
#define NC_ (F_ * 8 * 9)               // coeff pack work items = 2304

typedef _Float16 hvec2 __attribute__((ext_vector_type(2)));

// Single merged prolog: pads+packs x (half2 of channels c,c+8) AND packs coeffs.
__global__ __launch_bounds__(256)
void pack_kernel(const float* __restrict__ x,
                 const float* __restrict__ nums, const float* __restrict__ denoms,
                 __half2* __restrict__ xw, __half2* __restrict__ cw) {
    const int i = blockIdx.x * 256 + threadIdx.x;
    if (i < XN_) {
        const int cc = i % S_;
        int t = i / S_;
        const int r  = t % S_;
        t /= S_;
        const int pr = t % 8;
        const int b  = t / 8;
        float lo = 0.f, hi = 0.f;
        if (r >= 1 && r <= H_ && cc >= 1 && cc <= W_) {
            const int sp = (r - 1) * W_ + (cc - 1);
            lo = x[((size_t)(b * C_ + pr)     ) * (H_ * W_) + sp];
            hi = x[((size_t)(b * C_ + pr + 8)) * (H_ * W_) + sp];
        }
        xw[i] = __halves2half2(__float2half_rn(lo), __float2half_rn(hi));
    } else if (i < XN_ + NC_) {
        const int k = i - XN_;          // (f, pr, tap)
        const int tap = k % 9;
        const int pr  = (k / 9) % 8;
        const int f   = k / 72;
        __half2* o = cw + ((size_t)(f * 8 + pr) * 9 + tap) * 10;
        const size_t nlo = (((size_t)f * C_ + pr)     * 9 + tap) * 6;
        const size_t nhi = (((size_t)f * C_ + pr + 8) * 9 + tap) * 6;
        for (int q = 0; q < 6; ++q)
            o[q] = __halves2half2(__float2half_rn(nums[nlo + q]), __float2half_rn(nums[nhi + q]));
        const size_t dlo = (((size_t)f * C_ + pr)     * 9 + tap) * 4;
        const size_t dhi = (((size_t)f * C_ + pr + 8) * 9 + tap) * 4;
        for (int q = 0; q < 4; ++q)
            o[6 + q] = __halves2half2(__float2half_rn(denoms[dlo + q]), __float2half_rn(denoms[dhi + q]));
    }
}

// Main: 8 px/thread x 1 channel-pair/thread, f16 packed eval, s_load coeffs.
// Block 512 = 64 cols x 8 pair-groups; grid 1024 -> 8192 waves.
// __launch_bounds__(512, 8): 8 waves/EU -> caps VGPR at 64 so 32 waves/CU are
// genuinely resident. Live set ~55 regs (rv 30 + acc 8 + temps) -> no spill;
// this pins the allocator under the 64-reg occupancy cliff that the 72-way
// unrolled eval body otherwise overruns (R6 lesson, unverifiable since R12
// because rocprof top-k keeps returning fill kernels).
__global__ __launch_bounds__(512, 8)
void ka_rconv_kernel(const __half2* __restrict__ xw,
                     const __half2* __restrict__ cw,
                     float* __restrict__ out) {
    __shared__ float red[8 * 8 * 64];   // 16 KB: [group][px][col]

    const int tid = threadIdx.x;
    const int col = tid & 63;
    const int wg  = tid >> 6;          // pair index 0..7 (wave-uniform)

    int bid = blockIdx.x;
    const int f  = bid & 31;  bid >>= 5;
    const int t8 = bid & 7;   bid >>= 3;
    const int b  = bid;
    const int gy0 = t8 * 8;

    const int pr = __builtin_amdgcn_readfirstlane(wg);
    const __half2* ce = cw + (size_t)(f * 8 + pr) * CPAIR;   // uniform -> s_load
    const __half2* xbase = xw + ((size_t)(b * 8 + pr) * S_ + gy0) * S_ + col;

    const __half2 one = __halves2half2(__half(1.0f), __half(1.0f));
    float acc[8] = {0.f, 0.f, 0.f, 0.f, 0.f, 0.f, 0.f, 0.f};

    uint3 rv[10];    // 10 padded rows x 3 consecutive half2 (cols col..col+2)
    #pragma unroll
    for (int k = 0; k < 10; ++k)
        rv[k] = *(const uint3*)(xbase + k * S_);   // global_load_dwordx3

    #pragma unroll
    for (int t = 0; t < 9; ++t) {
        const __half2 n0 = ce[t*10+0], n1 = ce[t*10+1], n2 = ce[t*10+2];
        const __half2 n3 = ce[t*10+3], n4 = ce[t*10+4], n5 = ce[t*10+5];
        const __half2 d0 = ce[t*10+6], d1 = ce[t*10+7];
        const __half2 d2 = ce[t*10+8], d3 = ce[t*10+9];
        const int a = t / 3, j = t % 3;
        #pragma unroll
        for (int p = 0; p < 8; ++p) {
            const uint3 r3 = rv[p + a];
            const unsigned u = (j == 0) ? r3.x : (j == 1) ? r3.y : r3.z;
            const __half2 xp = __builtin_bit_cast(__half2, u);

            __half2 P = __hfma2(n5, xp, n4);
            P = __hfma2(P, xp, n3);
            P = __hfma2(P, xp, n2);
            P = __hfma2(P, xp, n1);
            P = __hfma2(P, xp, n0);

            __half2 Sd = __hfma2(d3, xp, d2);
            Sd = __hfma2(Sd, xp, d1);
            Sd = __hfma2(Sd, xp, d0);
            Sd = __hmul2(Sd, xp);

            const __half2 Q = __hadd2(one, __habs2(Sd));
            const __half2 R = h2rcp(Q);
            acc[p] = __builtin_amdgcn_fdot2(__builtin_bit_cast(hvec2, P),
                                            __builtin_bit_cast(hvec2, R),
                                            acc[p], false);
        }
    }

    // Balanced reduction: every wave writes its 8 partials; after the barrier
    // wave wg sums pixel-row wg across all 8 groups (no single-wave tail).
    #pragma unroll
    for (int p = 0; p < 8; ++p)
        red[(wg * 8 + p) * 64 + col] = acc[p];
    __syncthreads();
    float s = 0.f;
    #pragma unroll
    for (int q = 0; q < 8; ++q)
        s += red[(q * 8 + wg) * 64 + col];
    out[(((size_t)b * F_ + f) * H_ + gy0 + wg) * W_ + col] = s;
}

extern "C" void kernel_launch(void* const* d_in, const int* in_sizes, int n_in,
                              void* d_out, int out_size, void* d_ws, size_t ws_size,
                              hipStream_t stream) {
    const float* x      = (const float*)d_in[0];
    const float* nums   = (const float*)d_in[1];
    const float* denoms = (const float*)d_in[2];
    float* outp = (float*)d_out;
    __half2* xw = (__half2*)d_ws;                    // XN_ entries
    __half2* cwp = xw + XN_;                         // F_*8*CPAIR entries

    pack_kernel<<<(XN_ + NC_ + 255) / 256, 256, 0, stream>>>(x, nums, denoms, xw, cwp);
    dim3 grid(B_ * 8 * F_);   // 1024 blocks: (b, 8-row tile, f)
    ka_rconv_kernel<<<grid, 512, 0, stream>>>(xw, cwp, outp);
}

// Round 17
// 77.994 us; speedup vs baseline: 1.0691x; 1.0691x over previous
//
#include <hip/hip_runtime.h>
#include <hip/hip_fp16.h>

#define B_ 4
#define C_ 16
#define H_ 64
#define W_ 64
#define F_ 32
#define S_ 66
#define CHW_ (S_ * S_)                 // padded plane = 4356
#define XN_ (B_ * 8 * CHW_)            // packed x entries (half2 ch-pairs) = 139392
#define CPAIR 90                       // half2 per (f,pair): 9 taps x (6 n + 4 d)
#define NC_ (F_ * 8 * 9)               // coeff pack work items = 2304

typedef _Float16 hvec2 __attribute__((ext_vector_type(2)));

// Single merged prolog: pads+packs x (half2 of channels c,c+8) AND packs coeffs.
__global__ __launch_bounds__(256)
void pack_kernel(const float* __restrict__ x,
                 const float* __restrict__ nums, const float* __restrict__ denoms,
                 __half2* __restrict__ xw, __half2* __restrict__ cw) {
    const int i = blockIdx.x * 256 + threadIdx.x;
    if (i < XN_) {
        const int cc = i % S_;
        int t = i / S_;
        const int r  = t % S_;
        t /= S_;
        const int pr = t % 8;
        const int b  = t / 8;
        float lo = 0.f, hi = 0.f;
        if (r >= 1 && r <= H_ && cc >= 1 && cc <= W_) {
            const int sp = (r - 1) * W_ + (cc - 1);
            lo = x[((size_t)(b * C_ + pr)     ) * (H_ * W_) + sp];
            hi = x[((size_t)(b * C_ + pr + 8)) * (H_ * W_) + sp];
        }
        xw[i] = __halves2half2(__float2half_rn(lo), __float2half_rn(hi));
    } else if (i < XN_ + NC_) {
        const int k = i - XN_;          // (f, pr, tap)
        const int tap = k % 9;
        const int pr  = (k / 9) % 8;
        const int f   = k / 72;
        __half2* o = cw + ((size_t)(f * 8 + pr) * 9 + tap) * 10;
        const size_t nlo = (((size_t)f * C_ + pr)     * 9 + tap) * 6;
        const size_t nhi = (((size_t)f * C_ + pr + 8) * 9 + tap) * 6;
        for (int q = 0; q < 6; ++q)
            o[q] = __halves2half2(__float2half_rn(nums[nlo + q]), __float2half_rn(nums[nhi + q]));
        const size_t dlo = (((size_t)f * C_ + pr)     * 9 + tap) * 4;
        const size_t dhi = (((size_t)f * C_ + pr + 8) * 9 + tap) * 4;
        for (int q = 0; q < 4; ++q)
            o[6 + q] = __halves2half2(__float2half_rn(denoms[dlo + q]), __float2half_rn(denoms[dhi + q]));
    }
}

// Main: 4 px/thread x 1 channel-pair/thread, f16 packed eval, s_load coeffs.
// Block 512 = 64 cols x 8 pair-groups, covers a 4-row tile of one (b,f).
// Grid 2048 -> 16384 waves (two full 32-wave/CU rounds).
// R16 discriminator: forcing VGPR<=64 on the 8px body REGRESSED -> its natural
// live set is >64 (4 waves/SIMD). Here the live set is naturally small
// (rv[6]x3=18 + acc4 + temps ~= 45) so the allocator lands under the 64-reg
// cliff WITHOUT coercion -> genuine 8 waves/SIMD. No min-waves clause.
__global__ __launch_bounds__(512)
void ka_rconv_kernel(const __half2* __restrict__ xw,
                     const __half2* __restrict__ cw,
                     float* __restrict__ out) {
    __shared__ float red[8 * 4 * 64];   // 8 KB: [group][px][col]

    const int tid = threadIdx.x;
    const int col = tid & 63;
    const int wg  = tid >> 6;          // pair index 0..7 (wave-uniform)

    int bid = blockIdx.x;
    const int f  = bid & 31;  bid >>= 5;
    const int t4 = bid & 15;  bid >>= 4;
    const int b  = bid;
    const int gy0 = t4 * 4;

    const int pr = __builtin_amdgcn_readfirstlane(wg);
    const __half2* ce = cw + (size_t)(f * 8 + pr) * CPAIR;   // uniform -> s_load
    const __half2* xbase = xw + ((size_t)(b * 8 + pr) * S_ + gy0) * S_ + col;

    const __half2 one = __halves2half2(__half(1.0f), __half(1.0f));
    float acc[4] = {0.f, 0.f, 0.f, 0.f};

    uint3 rv[6];     // 6 padded rows x 3 consecutive half2 (cols col..col+2)
    #pragma unroll
    for (int k = 0; k < 6; ++k)
        rv[k] = *(const uint3*)(xbase + k * S_);   // global_load_dwordx3

    #pragma unroll
    for (int t = 0; t < 9; ++t) {
        const __half2 n0 = ce[t*10+0], n1 = ce[t*10+1], n2 = ce[t*10+2];
        const __half2 n3 = ce[t*10+3], n4 = ce[t*10+4], n5 = ce[t*10+5];
        const __half2 d0 = ce[t*10+6], d1 = ce[t*10+7];
        const __half2 d2 = ce[t*10+8], d3 = ce[t*10+9];
        const int a = t / 3, j = t % 3;
        #pragma unroll
        for (int p = 0; p < 4; ++p) {
            const uint3 r3 = rv[p + a];
            const unsigned u = (j == 0) ? r3.x : (j == 1) ? r3.y : r3.z;
            const __half2 xp = __builtin_bit_cast(__half2, u);

            __half2 P = __hfma2(n5, xp, n4);
            P = __hfma2(P, xp, n3);
            P = __hfma2(P, xp, n2);
            P = __hfma2(P, xp, n1);
            P = __hfma2(P, xp, n0);

            __half2 Sd = __hfma2(d3, xp, d2);
            Sd = __hfma2(Sd, xp, d1);
            Sd = __hfma2(Sd, xp, d0);
            Sd = __hmul2(Sd, xp);

            const __half2 Q = __hadd2(one, __habs2(Sd));
            const __half2 R = h2rcp(Q);
            acc[p] = __builtin_amdgcn_fdot2(__builtin_bit_cast(hvec2, P),
                                            __builtin_bit_cast(hvec2, R),
                                            acc[p], false);
        }
    }

    // Reduction: all 8 waves write partials; waves 0..3 sum row wg across groups.
    #pragma unroll
    for (int p = 0; p < 4; ++p)
        red[(wg * 4 + p) * 64 + col] = acc[p];
    __syncthreads();
    if (wg < 4) {
        float s = 0.f;
        #pragma unroll
        for (int q = 0; q < 8; ++q)
            s += red[(q * 4 + wg) * 64 + col];
        out[(((size_t)b * F_ + f) * H_ + gy0 + wg) * W_ + col] = s;
    }
}

extern "C" void kernel_launch(void* const* d_in, const int* in_sizes, int n_in,
                              void* d_out, int out_size, void* d_ws, size_t ws_size,
                              hipStream_t stream) {
    const float* x      = (const float*)d_in[0];
    const float* nums   = (const float*)d_in[1];
    const float* denoms = (const float*)d_in[2];
    float* outp = (float*)d_out;
    __half2* xw = (__half2*)d_ws;                    // XN_ entries
    __half2* cwp = xw + XN_;                         // F_*8*CPAIR entries

    pack_kernel<<<(XN_ + NC_ + 255) / 256, 256, 0, stream>>>(x, nums, denoms, xw, cwp);
    dim3 grid(B_ * 16 * F_);   // 2048 blocks: (b, 4-row tile, f)
    ka_rconv_kernel<<<grid, 512, 0, stream>>>(xw, cwp, outp);
}